// Round 2
// baseline (1661.147 us; speedup 1.0000x reference)
//
#include <hip/hip_runtime.h>
#include <hip/hip_bf16.h>
#include <math.h>

// VariableSelectionNetwork (TFT-style), B=32,T=512,V=16,D=128, all f32.
// Fused single kernel: per block, R=8 rows; per-var GRNs + LN -> stacked (LDS),
// softmax GRN -> weights, weighted sum -> processed.
#define NV 16
#define ND 128
#define NR 8          // rows per block
#define NTH 256
#define NROWS 16384   // 32*512

__device__ __forceinline__ float eluf(float x){ return x > 0.f ? x : expm1f(x); }
__device__ __forceinline__ float sigm(float x){ return 1.f / (1.f + expf(-x)); }

__global__ __launch_bounds__(NTH, 2)
void vsn_kernel(const float* __restrict__ x,
                const float* __restrict__ W1, const float* __restrict__ b1,
                const float* __restrict__ W2, const float* __restrict__ b2,
                const float* __restrict__ Wg, const float* __restrict__ bg,
                const float* __restrict__ Ws, const float* __restrict__ bs,
                const float* __restrict__ gamma, const float* __restrict__ beta,
                const float* __restrict__ sW1, const float* __restrict__ sb1,
                const float* __restrict__ sW2, const float* __restrict__ sb2,
                const float* __restrict__ sWg, const float* __restrict__ sbg,
                const float* __restrict__ sWs, const float* __restrict__ sbs,
                const float* __restrict__ sgamma, const float* __restrict__ sbeta,
                float* __restrict__ out_proc, float* __restrict__ out_w)
{
    __shared__ float sx[NR][NV];
    __shared__ float sh[NR][ND];
    __shared__ float shs[NR][ND];
    __shared__ float sstk[NR][NV*ND];
    __shared__ float ssk[NR][NV];
    __shared__ float sw[NR][NV];

    const int t = threadIdx.x;
    const int row0 = blockIdx.x * NR;

    if (t < NR*NV) sx[t>>4][t&15] = x[row0*NV + t];
    __syncthreads();

    const int o    = t & (ND-1);
    const int half = t >> 7;          // 0 or 1
    const int r0   = half * (NR/2);   // rows r0..r0+3

    // ---------------- per-variable GRNs ----------------
    for (int v = 0; v < NV; ++v) {
        // (a) h = elu(x*W1 + b1)
        #pragma unroll
        for (int i = 0; i < (NR*ND)/NTH; ++i) {
            int idx = i*NTH + t;
            int r = idx >> 7, d = idx & (ND-1);
            sh[r][d] = eluf(sx[r][v] * W1[v*ND + d] + b1[v*ND + d]);
        }
        __syncthreads();

        // (b) h2 = h.W2, gpre = h.Wg ; gate-mix with skip
        float acc2[NR/2] = {0.f,0.f,0.f,0.f};
        float accg[NR/2] = {0.f,0.f,0.f,0.f};
        const float4* w2p = reinterpret_cast<const float4*>(&W2[(v*ND + o)*ND]);
        const float4* wgp = reinterpret_cast<const float4*>(&Wg[(v*ND + o)*ND]);
        for (int d4 = 0; d4 < ND/4; ++d4) {
            float4 w2 = w2p[d4];
            float4 wg = wgp[d4];
            #pragma unroll
            for (int j = 0; j < NR/2; ++j) {
                const float4 hh = reinterpret_cast<const float4*>(&sh[r0+j][0])[d4];
                acc2[j] += hh.x*w2.x + hh.y*w2.y + hh.z*w2.z + hh.w*w2.w;
                accg[j] += hh.x*wg.x + hh.y*wg.y + hh.z*wg.z + hh.w*wg.w;
            }
        }
        const float b2v = b2[v*ND+o], bgv = bg[v*ND+o];
        const float wsv = Ws[v*ND+o], bsv = bs[v*ND+o];
        #pragma unroll
        for (int j = 0; j < NR/2; ++j) {
            int r = r0 + j;
            float h2   = acc2[j] + b2v;
            float g    = sigm(accg[j] + bgv);
            float skip = sx[r][v] * wsv + bsv;
            sstk[r][v*ND + o] = g*h2 + (1.f-g)*skip;
        }
        __syncthreads();

        // (c) LayerNorm over D for this v (32 threads per row)
        {
            int rr = t >> 5;
            int lane = t & 31;
            float vals[4];
            float s = 0.f, s2 = 0.f;
            #pragma unroll
            for (int j = 0; j < 4; ++j) {
                int oo = lane*4 + j;
                float y = sstk[rr][v*ND + oo];
                vals[j] = y; s += y; s2 += y*y;
            }
            #pragma unroll
            for (int m = 16; m >= 1; m >>= 1) {
                s  += __shfl_xor(s,  m, 32);
                s2 += __shfl_xor(s2, m, 32);
            }
            float mean = s * (1.f/ND);
            float var  = s2 * (1.f/ND) - mean*mean;
            float inv  = rsqrtf(var + 1e-5f);
            #pragma unroll
            for (int j = 0; j < 4; ++j) {
                int oo = lane*4 + j;
                sstk[rr][v*ND + oo] = (vals[j]-mean)*inv*gamma[v*ND+oo] + beta[v*ND+oo];
            }
        }
        __syncthreads();
    }

    // ---------------- softmax GRN ----------------
    // (2a) hs = elu(flat . sW1^T + sb1) ; every thread: one d, 4 rows
    {
        float acc[NR/2] = {0.f,0.f,0.f,0.f};
        const float4* wp = reinterpret_cast<const float4*>(&sW1[o * (NV*ND)]);
        for (int k4 = 0; k4 < (NV*ND)/4; ++k4) {
            float4 w = wp[k4];
            #pragma unroll
            for (int j = 0; j < NR/2; ++j) {
                const float4 f = reinterpret_cast<const float4*>(&sstk[r0+j][0])[k4];
                acc[j] += f.x*w.x + f.y*w.y + f.z*w.z + f.w*w.w;
            }
        }
        float bb = sb1[o];
        #pragma unroll
        for (int j = 0; j < NR/2; ++j) shs[r0+j][o] = eluf(acc[j] + bb);
    }
    // (2b) sks = flat . sWs^T + sbs  (threads 0..127: one (row,var) each)
    if (t < NR*NV) {
        int rr = t >> 4, vv = t & 15;
        const float4* wp = reinterpret_cast<const float4*>(&sWs[vv * (NV*ND)]);
        float acc = 0.f;
        for (int k4 = 0; k4 < (NV*ND)/4; ++k4) {
            float4 w = wp[k4];
            const float4 f = reinterpret_cast<const float4*>(&sstk[rr][0])[k4];
            acc += f.x*w.x + f.y*w.y + f.z*w.z + f.w*w.w;
        }
        ssk[rr][vv] = acc + sbs[vv];
    }
    __syncthreads();

    // (3) h2s/gs, gate-mix, LN over V, softmax -> weights
    if (t < NR*NV) {
        int rr = t >> 4, vv = t & 15;
        float a2 = 0.f, ag = 0.f;
        const float* w2p = &sW2[vv*ND];
        const float* wgp = &sWg[vv*ND];
        for (int d = 0; d < ND; ++d) {
            float hh = shs[rr][d];
            a2 += hh * w2p[d];
            ag += hh * wgp[d];
        }
        float h2s = a2 + sb2[vv];
        float gs  = sigm(ag + sbg[vv]);
        float yv  = gs*h2s + (1.f-gs)*ssk[rr][vv];
        float s = yv, s2 = yv*yv;
        #pragma unroll
        for (int m = 8; m >= 1; m >>= 1) {
            s  += __shfl_xor(s,  m, 16);
            s2 += __shfl_xor(s2, m, 16);
        }
        float mean = s * (1.f/NV);
        float var  = s2 * (1.f/NV) - mean*mean;
        float z = (yv-mean)*rsqrtf(var+1e-5f)*sgamma[vv] + sbeta[vv];
        float mx = z;
        #pragma unroll
        for (int m = 8; m >= 1; m >>= 1) mx = fmaxf(mx, __shfl_xor(mx, m, 16));
        float e = expf(z - mx);
        float es = e;
        #pragma unroll
        for (int m = 8; m >= 1; m >>= 1) es += __shfl_xor(es, m, 16);
        float w = e / es;
        sw[rr][vv] = w;
        out_w[(row0+rr)*NV + vv] = w;
    }
    __syncthreads();

    // (4) processed = sum_v stacked * weights
    #pragma unroll
    for (int i = 0; i < (NR*ND)/NTH; ++i) {
        int idx = i*NTH + t;
        int rr = idx >> 7, d = idx & (ND-1);
        float acc = 0.f;
        #pragma unroll
        for (int v = 0; v < NV; ++v) acc += sstk[rr][v*ND + d] * sw[rr][v];
        out_proc[(row0+rr)*ND + d] = acc;
    }
}

extern "C" void kernel_launch(void* const* d_in, const int* in_sizes, int n_in,
                              void* d_out, int out_size, void* d_ws, size_t ws_size,
                              hipStream_t stream) {
    (void)in_sizes; (void)n_in; (void)d_ws; (void)ws_size; (void)out_size;
    const float* x     = (const float*)d_in[0];
    const float* W1    = (const float*)d_in[1];
    const float* b1    = (const float*)d_in[2];
    const float* W2    = (const float*)d_in[3];
    const float* b2    = (const float*)d_in[4];
    const float* Wg    = (const float*)d_in[5];
    const float* bg    = (const float*)d_in[6];
    const float* Ws    = (const float*)d_in[7];
    const float* bs    = (const float*)d_in[8];
    const float* gamma = (const float*)d_in[9];
    const float* beta  = (const float*)d_in[10];
    const float* sW1   = (const float*)d_in[11];
    const float* sb1   = (const float*)d_in[12];
    const float* sW2   = (const float*)d_in[13];
    const float* sb2   = (const float*)d_in[14];
    const float* sWg   = (const float*)d_in[15];
    const float* sbg   = (const float*)d_in[16];
    const float* sWs   = (const float*)d_in[17];
    const float* sbs   = (const float*)d_in[18];
    const float* sgam  = (const float*)d_in[19];
    const float* sbet  = (const float*)d_in[20];

    float* out_proc = (float*)d_out;
    float* out_w    = out_proc + (size_t)NROWS * ND;

    dim3 grid(NROWS / NR), block(NTH);
    vsn_kernel<<<grid, block, 0, stream>>>(x, W1, b1, W2, b2, Wg, bg, Ws, bs,
                                           gamma, beta, sW1, sb1, sW2, sb2,
                                           sWg, sbg, sWs, sbs, sgam, sbet,
                                           out_proc, out_w);
}

// Round 3
// 241.639 us; speedup vs baseline: 6.8745x; 6.8745x over previous
//
#include <hip/hip_runtime.h>
#include <hip/hip_bf16.h>
#include <math.h>

// VSN fused: B=32,T=512,V=16,D=128. bf16 MFMA for all matmul phases.
#define NVAR 16
#define ND 128
#define NVD 2048
#define NR 16          // rows per block
#define NTH 512        // 8 waves
#define NROWS 16384
#define NBLK (NROWS/NR)

typedef short s16x8 __attribute__((ext_vector_type(8)));
typedef float f32x4 __attribute__((ext_vector_type(4)));
typedef unsigned short u16;

#define MFMA(a,b,c) __builtin_amdgcn_mfma_f32_16x16x32_bf16((a),(b),(c),0,0,0)

// ws layout (u16 elements)
#define OFF_W2  0
#define OFF_WG  262144
#define OFF_SW1 524288
#define OFF_SWS 786432
#define OFF_SW2 819200
#define OFF_SWG 821248
#define WS_ELEMS 823296

__device__ __forceinline__ unsigned f2bf(float f){
    union { float f; unsigned u; } c; c.f = f;
    unsigned u = c.u;
    u += 0x7fffu + ((u >> 16) & 1u);   // RNE
    return u >> 16;
}
__device__ __forceinline__ float bf2f(unsigned bits){
    union { unsigned u; float f; } c; c.u = bits << 16;
    return c.f;
}
__device__ __forceinline__ float eluf(float x){ return x > 0.f ? x : expm1f(x); }
__device__ __forceinline__ float sigm(float x){ return 1.f/(1.f+expf(-x)); }

// XOR-swizzled LDS offsets (u16 units). Row stride 2048 (resp 128) elems is
// bank-aligned; swizzle 16B units by row&7 -> ~2-way (free) on frag reads.
__device__ __forceinline__ int offBig(int r, int c){
    return r*2048 + ((((c>>3) ^ (r&7))<<3) | (c&7));
}
__device__ __forceinline__ int offHs(int r, int c){
    return r*128 + ((((c>>3) ^ (r&7))<<3) | (c&7));
}

__global__ void prep_kernel(const float* __restrict__ W2, const float* __restrict__ Wg,
                            const float* __restrict__ sW1, const float* __restrict__ sWs,
                            const float* __restrict__ sW2, const float* __restrict__ sWg,
                            u16* __restrict__ ws){
    int i = blockIdx.x*256 + threadIdx.x;
    if (i >= WS_ELEMS) return;
    float v;
    if      (i < OFF_WG)  v = W2[i];
    else if (i < OFF_SW1) v = Wg[i-OFF_WG];
    else if (i < OFF_SWS) v = sW1[i-OFF_SW1];
    else if (i < OFF_SW2) v = sWs[i-OFF_SWS];
    else if (i < OFF_SWG) v = sW2[i-OFF_SW2];
    else                  v = sWg[i-OFF_SWG];
    ws[i] = (u16)f2bf(v);
}

__global__ __launch_bounds__(NTH, 4)
void vsn_main(const float* __restrict__ x,
              const float* __restrict__ W1, const float* __restrict__ b1,
              const float* __restrict__ b2, const float* __restrict__ bg,
              const float* __restrict__ Wsk, const float* __restrict__ bsk,
              const float* __restrict__ gamma, const float* __restrict__ beta,
              const float* __restrict__ sb1, const float* __restrict__ sb2,
              const float* __restrict__ sbg, const float* __restrict__ sbs,
              const float* __restrict__ sgamma, const float* __restrict__ sbeta,
              const u16* __restrict__ ws,
              float* __restrict__ out_proc, float* __restrict__ out_w)
{
    __shared__ u16   big[NR*2048];   // h (per-v, transient) then stacked bf16, swizzled
    __shared__ u16   hsb[NR*128];    // hs bf16, swizzled
    __shared__ float pp[8*256];      // cross-wave MFMA partials
    __shared__ float psumbuf[256];   // LN partials [row][wave] x2 ; later: softmax weights
    __shared__ float sksbuf[256];    // rowstat (0..31) during loop; later: sks
    __shared__ float sx[NR*NVAR];

    float* psum  = psumbuf;
    float* psum2 = psumbuf + 128;

    const int t   = threadIdx.x;
    const int w   = t >> 6;
    const int l   = t & 63;
    const int hr  = l >> 4;        // 0..3
    const int c16 = l & 15;
    const int row0 = blockIdx.x * NR;
    const int orow = w*16 + c16;   // this wave's output column 0..127

    if (t < NR*NVAR) sx[t] = x[row0*NVAR + t];
    __syncthreads();

    const u16* W2b = ws + OFF_W2;
    const u16* Wgb = ws + OFF_WG;

    // ---------------- per-variable GRNs ----------------
    for (int v = 0; v < NVAR; ++v){
        // (a) h = elu(x*W1+b1) -> big chunk v (bf16, swizzled)
        #pragma unroll
        for (int i = 0; i < (NR*ND)/NTH; ++i){
            int idx = i*NTH + t;
            int r = idx >> 7, d = idx & 127;
            float hv = eluf(sx[r*NVAR+v]*W1[v*ND+d] + b1[v*ND+d]);
            big[offBig(r, v*ND+d)] = (u16)f2bf(hv);
        }
        __syncthreads();   // h ready (also covers prev v's stacked writes)

        // (b) MFMA: h2pre = h.W2^T cols, gpre = h.Wg^T cols (wave w owns cols w*16..+15)
        s16x8 A[4];
        #pragma unroll
        for (int ks = 0; ks < 4; ++ks)
            A[ks] = *reinterpret_cast<const s16x8*>(&big[offBig(c16, v*ND + ks*32 + hr*8)]);
        const s16x8* B2p = reinterpret_cast<const s16x8*>(W2b + v*ND*ND + orow*ND + hr*8);
        const s16x8* Bgp = reinterpret_cast<const s16x8*>(Wgb + v*ND*ND + orow*ND + hr*8);
        f32x4 acc2 = {0.f,0.f,0.f,0.f}, accg = {0.f,0.f,0.f,0.f};
        #pragma unroll
        for (int ks = 0; ks < 4; ++ks) acc2 = MFMA(A[ks], B2p[ks*4], acc2);
        #pragma unroll
        for (int ks = 0; ks < 4; ++ks) accg = MFMA(A[ks], Bgp[ks*4], accg);

        const float b2v = b2[v*ND+orow], bgv = bg[v*ND+orow];
        const float wsv = Wsk[v*ND+orow], bsv = bsk[v*ND+orow];
        float y[4];
        #pragma unroll
        for (int j = 0; j < 4; ++j){
            int r = hr*4 + j;                 // D-layout: row=(l>>4)*4+reg, col=l&15
            float h2 = acc2[j] + b2v;
            float g  = sigm(accg[j] + bgv);
            float sk = sx[r*NVAR+v]*wsv + bsv;
            y[j] = g*h2 + (1.f-g)*sk;
        }
        // LN partial sums over this wave's 16 cols (per row)
        float s[4], q[4];
        #pragma unroll
        for (int j=0;j<4;++j){ s[j]=y[j]; q[j]=y[j]*y[j]; }
        #pragma unroll
        for (int m=1; m<16; m<<=1){
            #pragma unroll
            for (int j=0;j<4;++j){
                s[j] += __shfl_xor(s[j], m, 16);
                q[j] += __shfl_xor(q[j], m, 16);
            }
        }
        if (c16 == 0){
            #pragma unroll
            for (int j=0;j<4;++j){
                psum [(hr*4+j)*8 + w] = s[j];
                psum2[(hr*4+j)*8 + w] = q[j];
            }
        }
        __syncthreads();

        if (t < NR){
            float ss=0.f, qq=0.f;
            #pragma unroll
            for (int ww=0; ww<8; ++ww){ ss += psum[t*8+ww]; qq += psum2[t*8+ww]; }
            float mean = ss*(1.f/ND);
            float var  = qq*(1.f/ND) - mean*mean;
            sksbuf[t]      = mean;
            sksbuf[16 + t] = rsqrtf(var + 1e-5f);
        }
        __syncthreads();

        // (d) normalize + gamma/beta, write stacked (in-place over h chunk v)
        const float gm = gamma[v*ND+orow], bt = beta[v*ND+orow];
        #pragma unroll
        for (int j=0;j<4;++j){
            int r = hr*4 + j;
            float z = (y[j]-sksbuf[r])*sksbuf[16+r]*gm + bt;
            big[offBig(r, v*ND+orow)] = (u16)f2bf(z);
        }
    }
    __syncthreads();   // stacked fully ready

    // ---------------- softmax GRN ----------------
    // (2a) hs = elu(flat . sW1^T + sb1): wave w -> output cols w*16..+15, K=2048
    const u16* sW1b = ws + OFF_SW1;
    {
        f32x4 acc0 = {0,0,0,0}, acc1 = {0,0,0,0};
        const s16x8* Bp = reinterpret_cast<const s16x8*>(sW1b + orow*NVD + hr*8);
        #pragma unroll 8
        for (int ks = 0; ks < 64; ks += 2){
            s16x8 A0 = *reinterpret_cast<const s16x8*>(&big[offBig(c16, ks*32 + hr*8)]);
            s16x8 A1 = *reinterpret_cast<const s16x8*>(&big[offBig(c16, (ks+1)*32 + hr*8)]);
            acc0 = MFMA(A0, Bp[ks*4],     acc0);
            acc1 = MFMA(A1, Bp[(ks+1)*4], acc1);
        }
        float bb = sb1[orow];
        #pragma unroll
        for (int j=0;j<4;++j){
            int r = hr*4 + j;
            hsb[offHs(r, orow)] = (u16)f2bf(eluf(acc0[j] + acc1[j] + bb));
        }
    }
    // (2b) sks partials: wave w covers ks = w*8..w*8+7 (K-split), N=16 vars
    const u16* sWsb = ws + OFF_SWS;
    {
        f32x4 acc = {0,0,0,0};
        const s16x8* Bp = reinterpret_cast<const s16x8*>(sWsb + c16*NVD + hr*8);
        #pragma unroll
        for (int kk = 0; kk < 8; ++kk){
            int ks = w*8 + kk;
            s16x8 Af = *reinterpret_cast<const s16x8*>(&big[offBig(c16, ks*32 + hr*8)]);
            acc = MFMA(Af, Bp[ks*4], acc);
        }
        #pragma unroll
        for (int j=0;j<4;++j)
            pp[w*256 + (hr*4+j)*16 + c16] = acc[j];
    }
    __syncthreads();   // hs + pp ready

    if (t < 256){
        float a = sbs[t & 15];
        #pragma unroll
        for (int ww=0; ww<8; ++ww) a += pp[ww*256 + t];
        sksbuf[t] = a;     // rowstat dead; sks = flat.sWs^T + sbs
    }
    __syncthreads();

    // (4) h2s / gs partials: waves 0-3 -> sW2 (ks=w), waves 4-7 -> sWg (ks=w-4)
    {
        const u16* Bsrc = (w < 4) ? (ws + OFF_SW2) : (ws + OFF_SWG);
        const int m = w & 3;
        s16x8 Af = *reinterpret_cast<const s16x8*>(&hsb[offHs(c16, m*32 + hr*8)]);
        s16x8 Bf = *reinterpret_cast<const s16x8*>(Bsrc + c16*ND + m*32 + hr*8);
        f32x4 z4 = {0,0,0,0};
        f32x4 acc = MFMA(Af, Bf, z4);
        #pragma unroll
        for (int j=0;j<4;++j)
            pp[w*256 + (hr*4+j)*16 + c16] = acc[j];
    }
    __syncthreads();

    // (5) gate-mix, LN over V, softmax -> weights
    if (t < 256){
        int r = t >> 4, vv = t & 15;
        float h2s = sb2[vv], gp = sbg[vv];
        #pragma unroll
        for (int j=0;j<4;++j){ h2s += pp[j*256 + t]; gp += pp[(4+j)*256 + t]; }
        float gs = sigm(gp);
        float yv = gs*h2s + (1.f-gs)*sksbuf[t];
        float ssum = yv, qsum = yv*yv;
        #pragma unroll
        for (int m=1;m<16;m<<=1){ ssum += __shfl_xor(ssum,m,16); qsum += __shfl_xor(qsum,m,16); }
        float mean = ssum*(1.f/NVAR);
        float var  = qsum*(1.f/NVAR) - mean*mean;
        float z = (yv-mean)*rsqrtf(var+1e-5f)*sgamma[vv] + sbeta[vv];
        float mx = z;
        #pragma unroll
        for (int m=1;m<16;m<<=1) mx = fmaxf(mx, __shfl_xor(mx,m,16));
        float e = expf(z-mx);
        float es = e;
        #pragma unroll
        for (int m=1;m<16;m<<=1) es += __shfl_xor(es,m,16);
        float wgt = e/es;
        psumbuf[t] = wgt;                       // psum region dead -> weights
        out_w[(row0+r)*NVAR + vv] = wgt;
    }
    __syncthreads();

    // (6) processed = sum_v stacked * weights
    #pragma unroll
    for (int i=0;i<(NR*ND)/NTH;++i){
        int idx = i*NTH + t;
        int r = idx >> 7, d = idx & 127;
        float acc = 0.f;
        #pragma unroll
        for (int v=0;v<NVAR;++v)
            acc += bf2f(big[offBig(r, v*ND+d)]) * psumbuf[r*NVAR+v];
        out_proc[(row0+r)*ND + d] = acc;
    }
}

extern "C" void kernel_launch(void* const* d_in, const int* in_sizes, int n_in,
                              void* d_out, int out_size, void* d_ws, size_t ws_size,
                              hipStream_t stream) {
    (void)in_sizes; (void)n_in; (void)out_size; (void)ws_size;
    const float* x     = (const float*)d_in[0];
    const float* W1    = (const float*)d_in[1];
    const float* b1    = (const float*)d_in[2];
    const float* W2    = (const float*)d_in[3];
    const float* b2    = (const float*)d_in[4];
    const float* Wg    = (const float*)d_in[5];
    const float* bg    = (const float*)d_in[6];
    const float* Wsk   = (const float*)d_in[7];
    const float* bsk   = (const float*)d_in[8];
    const float* gamma = (const float*)d_in[9];
    const float* beta  = (const float*)d_in[10];
    const float* sW1   = (const float*)d_in[11];
    const float* sb1   = (const float*)d_in[12];
    const float* sW2   = (const float*)d_in[13];
    const float* sb2   = (const float*)d_in[14];
    const float* sWg   = (const float*)d_in[15];
    const float* sbg   = (const float*)d_in[16];
    const float* sWs   = (const float*)d_in[17];
    const float* sbs   = (const float*)d_in[18];
    const float* sgam  = (const float*)d_in[19];
    const float* sbet  = (const float*)d_in[20];

    u16* ws = (u16*)d_ws;
    float* out_proc = (float*)d_out;
    float* out_w    = out_proc + (size_t)NROWS * ND;

    prep_kernel<<<(WS_ELEMS + 255)/256, 256, 0, stream>>>(W2, Wg, sW1, sWs, sW2, sWg, ws);
    vsn_main<<<NBLK, NTH, 0, stream>>>(x, W1, b1, b2, bg, Wsk, bsk, gamma, beta,
                                       sb1, sb2, sbg, sbs, sgam, sbet, ws,
                                       out_proc, out_w);
}